// Round 4
// baseline (158.295 us; speedup 1.0000x reference)
//
#include <hip/hip_runtime.h>
#include <cstdint>
#include <cstddef>

typedef unsigned short u16;
typedef __attribute__((ext_vector_type(8))) short short8;
typedef __attribute__((ext_vector_type(8))) unsigned short u16x8;
typedef __attribute__((ext_vector_type(4))) float f32x4;

#define NB   96
#define TO   50
#define TW   40
#define DD   512
#define MROWS (NB*TW)      /* 3840 */
#define BM   128
#define BK   32
#define NKC  (DD/BK)       /* 16 */

/* workspace layout (bytes) */
#define WBF_OFF   0u
#define OBF_OFF   (MROWS*DD*2u)              /* 3,932,160  */
#define LOG_OFF   (OBF_OFF + NB*TO*DD*2u)    /* 8,847,360  */
#define ZB_OFF    (LOG_OFF + MROWS*NB*4u)    /* 10,321,920 */

__device__ __forceinline__ u16 f2bf(float f) {
  unsigned int u = __builtin_bit_cast(unsigned int, f);
  u += 0x7fffu + ((u >> 16) & 1u);           /* RNE */
  return (u16)(u >> 16);
}

__device__ __forceinline__ void gload16(const void* g, void* l) {
  __builtin_amdgcn_global_load_lds(
      (__attribute__((address_space(1))) unsigned int*)(g),
      (__attribute__((address_space(3))) unsigned int*)(l), 16, 0, 0);
}

/* ------- kernel 0: f32 -> bf16 convert + zero pad buffer + zero out ------ */
__global__ void k_convert(const float* __restrict__ o, const float* __restrict__ w,
                          u16* __restrict__ obf, u16* __restrict__ wbf,
                          u16* __restrict__ zbuf, float* __restrict__ out) {
  const int stride = gridDim.x * blockDim.x;
  const int tid0 = blockIdx.x * blockDim.x + threadIdx.x;
  const int no8 = NB*TO*DD/8;
  const int nw8 = NB*TW*DD/8;
  for (int i = tid0; i < no8; i += stride) {
    const float4* s = (const float4*)o + (size_t)i*2;
    float4 a = s[0], b = s[1];
    u16x8 r = { f2bf(a.x), f2bf(a.y), f2bf(a.z), f2bf(a.w),
                f2bf(b.x), f2bf(b.y), f2bf(b.z), f2bf(b.w) };
    *(u16x8*)(obf + (size_t)i*8) = r;
  }
  for (int i = tid0; i < nw8; i += stride) {
    const float4* s = (const float4*)w + (size_t)i*2;
    float4 a = s[0], b = s[1];
    u16x8 r = { f2bf(a.x), f2bf(a.y), f2bf(a.z), f2bf(a.w),
                f2bf(b.x), f2bf(b.y), f2bf(b.z), f2bf(b.w) };
    *(u16x8*)(wbf + (size_t)i*8) = r;
  }
  if (tid0 < 16) {
    u16x8 z = {0,0,0,0,0,0,0,0};
    *(u16x8*)(zbuf + tid0*8) = z;
  }
  if (tid0 == 0) out[0] = 0.f;
}

/* ------- kernel 1: fused S=W·O^T GEMM + row softmax-weighted mean -------- */
/* grid: (48 ob-pairs, 30 row-tiles), 256 threads = 4 waves.
   wave (wid>>1) picks row half, (wid&1) picks ob: each wave owns a 64x64
   tile whose 64 columns are exactly one ob group -> softmax fully in-wave. */
__global__ void __launch_bounds__(256) k_main(
    const u16* __restrict__ wbf, const u16* __restrict__ obf,
    const u16* __restrict__ zbuf, float* __restrict__ logits) {
  __shared__ u16 ldsA[2][BM*BK];
  __shared__ u16 ldsB[2][BM*BK];
  const int tid  = threadIdx.x;
  const int lane = tid & 63;
  const int wid  = tid >> 6;
  const int r0   = blockIdx.y * BM;
  const int ob0  = blockIdx.x * 2;

  /* staging precompute: 16B chunk c = i*256 + tid; row = c>>2, kchunk = c&3 */
  const u16* gA[2];
  const u16* gB[2];
  bool realB[2];
  #pragma unroll
  for (int i = 0; i < 2; ++i) {
    int c   = i*256 + tid;
    int row = c >> 2;
    int kc8 = (c & 3) * 8;
    gA[i] = wbf + (size_t)(r0 + row) * DD + kc8;
    int ob = ob0 + (row >> 6);
    int oo = row & 63;
    realB[i] = (oo < TO);
    gB[i] = realB[i] ? (obf + ((size_t)ob * TO + oo) * DD + kc8) : zbuf;
  }
  const int ldst = (wid * 64) * 8;  /* wave-uniform LDS chunk base (elems) */

  auto stage = [&](int buf, int k0) {
    #pragma unroll
    for (int i = 0; i < 2; ++i) {
      gload16(gA[i] + k0, &ldsA[buf][i*2048 + ldst]);
      gload16(realB[i] ? gB[i] + k0 : gB[i], &ldsB[buf][i*2048 + ldst]);
    }
  };

  const int wr   = (wid >> 1) * 64;
  const int wc   = (wid & 1) * 64;
  const int lrow = lane & 15;
  const int lk   = (lane >> 4) * 8;

  f32x4 zero4 = {0.f, 0.f, 0.f, 0.f};
  f32x4 acc[4][4];
  #pragma unroll
  for (int mi = 0; mi < 4; ++mi)
    #pragma unroll
    for (int ni = 0; ni < 4; ++ni) acc[mi][ni] = zero4;

  stage(0, 0);
  for (int kc = 0; kc < NKC; ++kc) {
    const int cur = kc & 1;
    __syncthreads();                    /* drains vmcnt -> buf[cur] ready */
    if (kc + 1 < NKC) stage(cur ^ 1, (kc + 1) * BK);
    short8 af[4], bfr[4];
    #pragma unroll
    for (int mi = 0; mi < 4; ++mi)
      af[mi] = *(const short8*)&ldsA[cur][(wr + mi*16 + lrow) * BK + lk];
    #pragma unroll
    for (int ni = 0; ni < 4; ++ni)
      bfr[ni] = *(const short8*)&ldsB[cur][(wc + ni*16 + lrow) * BK + lk];
    #pragma unroll
    for (int mi = 0; mi < 4; ++mi)
      #pragma unroll
      for (int ni = 0; ni < 4; ++ni)
        acc[mi][ni] = __builtin_amdgcn_mfma_f32_16x16x32_bf16(
            af[mi], bfr[ni], acc[mi][ni], 0, 0, 0);
  }

  /* epilogue: per row (over this wave's 64 cols = one ob, 50 real):
     logits = sum(p*S_raw)/sum(p), p = exp(scale*(S_raw - max)).
     layout: logits[row][ob], row = wb*TW + t = flat W row. */
  const float scale = 0.04419417382415922f;  /* 1/sqrt(512) */
  const int ob = ob0 + (wid & 1);
  #pragma unroll
  for (int mi = 0; mi < 4; ++mi) {
    #pragma unroll
    for (int q = 0; q < 4; ++q) {
      float v0 = acc[mi][0][q], v1 = acc[mi][1][q],
            v2 = acc[mi][2][q], v3 = acc[mi][3][q];
      /* cols: ni*16+lrow ; ni<3 always real, ni=3 real iff lrow<2 */
      float m = fmaxf(fmaxf(v0, v1), v2);
      if (lrow < 2) m = fmaxf(m, v3);
      #pragma unroll
      for (int d = 1; d < 16; d <<= 1) m = fmaxf(m, __shfl_xor(m, d));
      float p0 = __expf((v0 - m) * scale);
      float p1 = __expf((v1 - m) * scale);
      float p2 = __expf((v2 - m) * scale);
      float den = p0 + p1 + p2;
      float num = p0*v0 + p1*v1 + p2*v2;
      if (lrow < 2) {
        float p3 = __expf((v3 - m) * scale);
        den += p3; num += p3*v3;
      }
      #pragma unroll
      for (int d = 1; d < 16; d <<= 1) {
        den += __shfl_xor(den, d);
        num += __shfl_xor(num, d);
      }
      if (lrow == 0) {
        int row = r0 + wr + mi*16 + (lane >> 4)*4 + q;
        logits[(size_t)row * NB + ob] = num / den;
      }
    }
  }
}

/* ---- kernel 2: one wave per row: LSE over 96 obs, diag logp, atomic ---- */
__global__ void __launch_bounds__(256) k_lse(
    const float* __restrict__ logits, float* __restrict__ out) {
  const int tid  = threadIdx.x;
  const int lane = tid & 63;
  const int wid  = tid >> 6;
  const int row  = blockIdx.x * 4 + wid;   /* 960 blocks * 4 waves = 3840 */
  const float* base = logits + (size_t)row * NB;
  float v0 = base[lane];
  float v1 = (lane < NB - 64) ? base[64 + lane] : -1e30f;
  float m = fmaxf(v0, v1);
  #pragma unroll
  for (int d = 1; d < 64; d <<= 1) m = fmaxf(m, __shfl_xor(m, d));
  float den = __expf(v0 - m) + ((lane < NB - 64) ? __expf(v1 - m) : 0.f);
  #pragma unroll
  for (int d = 1; d < 64; d <<= 1) den += __shfl_xor(den, d);
  if (lane == 0) {
    const int wb = row / TW;               /* diagonal ob index */
    float logp = base[wb] - m - __logf(den);
    atomicAdd(out, logp * (-1.0f / (float)MROWS));
  }
}

extern "C" void kernel_launch(void* const* d_in, const int* in_sizes, int n_in,
                              void* d_out, int out_size, void* d_ws, size_t ws_size,
                              hipStream_t stream) {
  const float* o = (const float*)d_in[0];   /* (96,50,512) f32 */
  const float* w = (const float*)d_in[1];   /* (96,40,512) f32 */
  char* ws = (char*)d_ws;
  u16*    wbf     = (u16*)(ws + WBF_OFF);
  u16*    obf     = (u16*)(ws + OBF_OFF);
  float*  logits  = (float*)(ws + LOG_OFF);
  u16*    zbuf    = (u16*)(ws + ZB_OFF);

  k_convert<<<1200, 256, 0, stream>>>(o, w, obf, wbf, zbuf, (float*)d_out);
  dim3 g1(NB/2, MROWS/BM);
  k_main<<<g1, 256, 0, stream>>>(wbf, obf, zbuf, logits);
  k_lse<<<960, 256, 0, stream>>>(logits, (float*)d_out);
}

// Round 5
// 115.580 us; speedup vs baseline: 1.3696x; 1.3696x over previous
//
#include <hip/hip_runtime.h>
#include <cstdint>
#include <cstddef>

typedef unsigned short u16;
typedef __attribute__((ext_vector_type(8))) short short8;
typedef __attribute__((ext_vector_type(8))) unsigned short u16x8;
typedef __attribute__((ext_vector_type(4))) float f32x4;

#define NB   96
#define TO   50
#define TW   40
#define DD   512
#define MROWS (NB*TW)      /* 3840 */
#define BM   128
#define BK   32
#define NKC  (DD/BK)       /* 16 */

/* workspace layout (bytes) */
#define WBF_OFF   0u
#define OBF_OFF   (MROWS*DD*2u)              /* 3,932,160  */
#define LOG_OFF   (OBF_OFF + NB*TO*DD*2u)    /* 8,847,360  */
#define ZB_OFF    (LOG_OFF + MROWS*NB*4u)    /* 10,321,920 */

__device__ __forceinline__ u16 f2bf(float f) {
  unsigned int u = __builtin_bit_cast(unsigned int, f);
  u += 0x7fffu + ((u >> 16) & 1u);           /* RNE */
  return (u16)(u >> 16);
}

__device__ __forceinline__ void gload16(const void* g, void* l) {
  __builtin_amdgcn_global_load_lds(
      (__attribute__((address_space(1))) unsigned int*)(g),
      (__attribute__((address_space(3))) unsigned int*)(l), 16, 0, 0);
}

/* ------- kernel 0: f32 -> bf16 convert + zero pad buffer + zero out ------ */
__global__ void k_convert(const float* __restrict__ o, const float* __restrict__ w,
                          u16* __restrict__ obf, u16* __restrict__ wbf,
                          u16* __restrict__ zbuf, float* __restrict__ out) {
  const int stride = gridDim.x * blockDim.x;
  const int tid0 = blockIdx.x * blockDim.x + threadIdx.x;
  const int no8 = NB*TO*DD/8;
  const int nw8 = NB*TW*DD/8;
  for (int i = tid0; i < no8; i += stride) {
    const float4* s = (const float4*)o + (size_t)i*2;
    float4 a = s[0], b = s[1];
    u16x8 r = { f2bf(a.x), f2bf(a.y), f2bf(a.z), f2bf(a.w),
                f2bf(b.x), f2bf(b.y), f2bf(b.z), f2bf(b.w) };
    *(u16x8*)(obf + (size_t)i*8) = r;
  }
  for (int i = tid0; i < nw8; i += stride) {
    const float4* s = (const float4*)w + (size_t)i*2;
    float4 a = s[0], b = s[1];
    u16x8 r = { f2bf(a.x), f2bf(a.y), f2bf(a.z), f2bf(a.w),
                f2bf(b.x), f2bf(b.y), f2bf(b.z), f2bf(b.w) };
    *(u16x8*)(wbf + (size_t)i*8) = r;
  }
  if (tid0 < 16) {
    u16x8 z = {0,0,0,0,0,0,0,0};
    *(u16x8*)(zbuf + tid0*8) = z;
  }
  if (tid0 == 0) out[0] = 0.f;
}

/* ------- kernel 1: fused S=W·O^T GEMM + row softmax-weighted mean -------- */
/* grid: (48 ob-pairs, 30 row-tiles), 256 threads = 4 waves.
   wave (wid>>1) picks row half, (wid&1) picks ob: each wave owns a 64x64
   tile whose 64 columns are exactly one ob group -> softmax fully in-wave. */
__global__ void __launch_bounds__(256) k_main(
    const u16* __restrict__ wbf, const u16* __restrict__ obf,
    const u16* __restrict__ zbuf, float* __restrict__ logits) {
  __shared__ u16 ldsA[2][BM*BK];
  __shared__ u16 ldsB[2][BM*BK];
  const int tid  = threadIdx.x;
  const int lane = tid & 63;
  const int wid  = tid >> 6;
  const int r0   = blockIdx.y * BM;
  const int ob0  = blockIdx.x * 2;

  /* staging precompute: 16B chunk c = i*256 + tid; row = c>>2, kchunk = c&3 */
  const u16* gA[2];
  const u16* gB[2];
  bool realB[2];
  #pragma unroll
  for (int i = 0; i < 2; ++i) {
    int c   = i*256 + tid;
    int row = c >> 2;
    int kc8 = (c & 3) * 8;
    gA[i] = wbf + (size_t)(r0 + row) * DD + kc8;
    int ob = ob0 + (row >> 6);
    int oo = row & 63;
    realB[i] = (oo < TO);
    gB[i] = realB[i] ? (obf + ((size_t)ob * TO + oo) * DD + kc8) : zbuf;
  }
  const int ldst = (wid * 64) * 8;  /* wave-uniform LDS chunk base (elems) */

  auto stage = [&](int buf, int k0) {
    #pragma unroll
    for (int i = 0; i < 2; ++i) {
      gload16(gA[i] + k0, &ldsA[buf][i*2048 + ldst]);
      gload16(realB[i] ? gB[i] + k0 : gB[i], &ldsB[buf][i*2048 + ldst]);
    }
  };

  const int wr   = (wid >> 1) * 64;
  const int wc   = (wid & 1) * 64;
  const int lrow = lane & 15;
  const int lk   = (lane >> 4) * 8;

  f32x4 zero4 = {0.f, 0.f, 0.f, 0.f};
  f32x4 acc[4][4];
  #pragma unroll
  for (int mi = 0; mi < 4; ++mi)
    #pragma unroll
    for (int ni = 0; ni < 4; ++ni) acc[mi][ni] = zero4;

  stage(0, 0);
  for (int kc = 0; kc < NKC; ++kc) {
    const int cur = kc & 1;
    __syncthreads();                    /* drains vmcnt -> buf[cur] ready */
    if (kc + 1 < NKC) stage(cur ^ 1, (kc + 1) * BK);
    short8 af[4], bfr[4];
    #pragma unroll
    for (int mi = 0; mi < 4; ++mi)
      af[mi] = *(const short8*)&ldsA[cur][(wr + mi*16 + lrow) * BK + lk];
    #pragma unroll
    for (int ni = 0; ni < 4; ++ni)
      bfr[ni] = *(const short8*)&ldsB[cur][(wc + ni*16 + lrow) * BK + lk];
    #pragma unroll
    for (int mi = 0; mi < 4; ++mi)
      #pragma unroll
      for (int ni = 0; ni < 4; ++ni)
        acc[mi][ni] = __builtin_amdgcn_mfma_f32_16x16x32_bf16(
            af[mi], bfr[ni], acc[mi][ni], 0, 0, 0);
  }

  /* epilogue: per row (over this wave's 64 cols = one ob, 50 real):
     logits = sum(p*S_raw)/sum(p), p = exp(scale*(S_raw - max)).
     layout: logits[row][ob], row = wb*TW + t = flat W row. */
  const float scale = 0.04419417382415922f;  /* 1/sqrt(512) */
  const int ob = ob0 + (wid & 1);
  #pragma unroll
  for (int mi = 0; mi < 4; ++mi) {
    #pragma unroll
    for (int q = 0; q < 4; ++q) {
      float v0 = acc[mi][0][q], v1 = acc[mi][1][q],
            v2 = acc[mi][2][q], v3 = acc[mi][3][q];
      /* cols: ni*16+lrow ; ni<3 always real, ni=3 real iff lrow<2 */
      float m = fmaxf(fmaxf(v0, v1), v2);
      if (lrow < 2) m = fmaxf(m, v3);
      #pragma unroll
      for (int d = 1; d < 16; d <<= 1) m = fmaxf(m, __shfl_xor(m, d));
      float p0 = __expf((v0 - m) * scale);
      float p1 = __expf((v1 - m) * scale);
      float p2 = __expf((v2 - m) * scale);
      float den = p0 + p1 + p2;
      float num = p0*v0 + p1*v1 + p2*v2;
      if (lrow < 2) {
        float p3 = __expf((v3 - m) * scale);
        den += p3; num += p3*v3;
      }
      #pragma unroll
      for (int d = 1; d < 16; d <<= 1) {
        den += __shfl_xor(den, d);
        num += __shfl_xor(num, d);
      }
      if (lrow == 0) {
        int row = r0 + wr + mi*16 + (lane >> 4)*4 + q;
        logits[(size_t)row * NB + ob] = num / den;
      }
    }
  }
}

/* ---- kernel 2: 60 blocks x 8 waves; each wave 8 rows; LSE over 96 obs;
       per-block LDS reduce -> ONE atomicAdd per block (60 total) ---------- */
__global__ void __launch_bounds__(512) k_lse(
    const float* __restrict__ logits, float* __restrict__ out) {
  __shared__ float red[8];
  const int tid  = threadIdx.x;
  const int lane = tid & 63;
  const int wid  = tid >> 6;                 /* 0..7 */
  const int gw   = blockIdx.x * 8 + wid;     /* 0..479 */
  float acc = 0.f;
  #pragma unroll
  for (int i = 0; i < 8; ++i) {
    const int row = gw * 8 + i;              /* 480*8 = 3840 rows */
    const float* base = logits + (size_t)row * NB;
    float v0 = base[lane];
    float v1 = (lane < NB - 64) ? base[64 + lane] : -1e30f;
    float m = fmaxf(v0, v1);
    #pragma unroll
    for (int d = 1; d < 64; d <<= 1) m = fmaxf(m, __shfl_xor(m, d));
    float den = __expf(v0 - m) + ((lane < NB - 64) ? __expf(v1 - m) : 0.f);
    #pragma unroll
    for (int d = 1; d < 64; d <<= 1) den += __shfl_xor(den, d);
    if (lane == 0) {
      const int wb = row / TW;               /* diagonal ob index */
      acc += base[wb] - m - __logf(den);
    }
  }
  if (lane == 0) red[wid] = acc;
  __syncthreads();
  if (tid == 0) {
    float s = red[0] + red[1] + red[2] + red[3]
            + red[4] + red[5] + red[6] + red[7];
    atomicAdd(out, s * (-1.0f / (float)MROWS));
  }
}

extern "C" void kernel_launch(void* const* d_in, const int* in_sizes, int n_in,
                              void* d_out, int out_size, void* d_ws, size_t ws_size,
                              hipStream_t stream) {
  const float* o = (const float*)d_in[0];   /* (96,50,512) f32 */
  const float* w = (const float*)d_in[1];   /* (96,40,512) f32 */
  char* ws = (char*)d_ws;
  u16*    wbf     = (u16*)(ws + WBF_OFF);
  u16*    obf     = (u16*)(ws + OBF_OFF);
  float*  logits  = (float*)(ws + LOG_OFF);
  u16*    zbuf    = (u16*)(ws + ZB_OFF);

  k_convert<<<1200, 256, 0, stream>>>(o, w, obf, wbf, zbuf, (float*)d_out);
  dim3 g1(NB/2, MROWS/BM);
  k_main<<<g1, 256, 0, stream>>>(wbf, obf, zbuf, logits);
  k_lse<<<60, 512, 0, stream>>>(logits, (float*)d_out);
}